// Round 10
// baseline (251.101 us; speedup 1.0000x reference)
//
#include <hip/hip_runtime.h>

// LTFGW semi-relaxed FGW — round 10.
// srfgw: BYTE-IDENTICAL to round 9 (190 us, VALU-bound at 85%, iter-0 fold).
// gcost v3: rounds 5-9 showed a constant ~55 us of non-srfgw time -> gcost
//   was ~45-50 us (4-5x static estimate): transposed-LDS staging was
//   DS-throughput + 16-barrier bound. v3 = no LDS, no barriers: each
//   HALF-WAVE owns one kt; F2 float4 preloaded in registers; per node:
//   coalesced x float4 load + 4 FMA + (4x DPP ror_add + ds_swizzle xor16)
//   reduce; lanes 0/32 store. ~6.5 instr/output, independent iterations.

#define NN    6000
#define DEG   16
#define MM    17
#define NTPL  16
#define MT    10
#define NF    128
#define NITER 10
#define KPB   16
#define NPB   3
#define BS    1024
#define RS    12            // padded T row stride (floats)
#define LOG2E 1.44269504088896340736f

template<int C>
__device__ __forceinline__ float ror_add(float v) {
    int s = __builtin_amdgcn_update_dpp(0, __float_as_int(v), C, 0xf, 0xf, true);
    return v + __int_as_float(s);
}

__device__ __forceinline__ float fexp2(float x) { return __builtin_amdgcn_exp2f(x); }
__device__ __forceinline__ float frcp(float x)  { return __builtin_amdgcn_rcpf(x); }

// sum over 32 consecutive lanes (result in all 32)
__device__ __forceinline__ float reduce32(float v) {
    v = ror_add<0x121>(v);
    v = ror_add<0x122>(v);
    v = ror_add<0x124>(v);
    v = ror_add<0x128>(v);
    int s = __builtin_amdgcn_ds_swizzle(__float_as_int(v), 0x401F); // xor lane^16
    return v + __int_as_float(s);
}

// ---------------- gcost v3: G[v,kt] = mcoefl*(||F2[kt]||^2 - 2 x[v].F2[kt])
#define GNV 30
__global__ __launch_bounds__(256) void gcost_kernel(
    const float* __restrict__ x, const float* __restrict__ F2g,
    const float* __restrict__ alpha0, float* __restrict__ G)
{
    const int wv   = threadIdx.x >> 6;       // 0..3
    const int ln   = threadIdx.x & 63;
    const int half = ln >> 5;                // 0/1
    const int l32  = ln & 31;
    const int kt   = blockIdx.y * 8 + wv * 2 + half;   // grid.y=20 -> 0..159

    const float4 f2 = reinterpret_cast<const float4*>(F2g + (size_t)kt * NF)[l32];
    float sq = reduce32(f2.x * f2.x + f2.y * f2.y + f2.z * f2.z + f2.w * f2.w);

    const float alpha  = 1.f / (1.f + __expf(-alpha0[0]));
    const float mcoefl = (1.f - alpha) * 10.f * LOG2E;

    const int v0 = blockIdx.x * GNV;
    #pragma unroll 2
    for (int i = 0; i < GNV; i++) {
        const int v = v0 + i;
        float4 xv = reinterpret_cast<const float4*>(x + (size_t)v * NF)[l32];
        float d = xv.x * f2.x + xv.y * f2.y + xv.z * f2.z + xv.w * f2.w;
        d = reduce32(d);
        if (l32 == 0)
            G[(size_t)v * (NTPL * MT) + kt] = mcoefl * (sq - 2.f * d);
    }
}

// ---------------- main kernel (round-9 verbatim)
__global__ __launch_bounds__(BS, 4) void srfgw_kernel(
    const float* __restrict__ x,
    const int*   __restrict__ dst,
    const float* __restrict__ C2g,
    const float* __restrict__ F2g,
    const float* __restrict__ alpha0,
    const float* __restrict__ G,
    int useG,
    float*       __restrict__ out)
{
    const int nb  = blockIdx.x * NPB;
    const int tid = threadIdx.x;

    __shared__ __align__(16) float s_T[KPB][NPB][MM][RS];     // 39168 B
    __shared__ __align__(16) float s_C2sq[KPB][MT][RS];       // 7680 B
    __shared__ __align__(16) float s_q[KPB][NPB][RS];         // 2304 B
    __shared__ __align__(16) float s_cc[KPB][NPB][RS];        // 2304 B
    __shared__ __align__(16) float s_A[KPB][RS];              // 768 B (iter-0 fold)
    __shared__ __align__(16) float s_B[KPB][RS];              // 768 B
    __shared__ __align__(16) int   s_adj[NPB * MM][DEG];      // 3264 B
    __shared__ int      s_nbr[NPB][MM];
    __shared__ unsigned s_mask[NPB][MM];

    const float aval  = alpha0[0];
    const float alpha = 1.f / (1.f + __expf(-aval));
    const float gcoef = 2.f * alpha * 10.f;
    const float tgl   = 2.f * gcoef * LOG2E;
    const float gl2   = gcoef * LOG2E;

    if (tid < NPB * MM) {
        int node = tid / MM, a0 = tid - node * MM;
        s_nbr[node][a0]  = (a0 == 0) ? (nb + node) : dst[(size_t)(nb + node) * DEG + a0 - 1];
        s_mask[node][a0] = 0u;
    }
    __syncthreads();

    if (tid < NPB * MM * DEG) {
        int r = tid >> 4, j = tid & 15;
        int node = r / MM, a0 = r - node * MM;
        s_adj[r][j] = dst[(size_t)s_nbr[node][a0] * DEG + j];
    }
    for (int i = tid; i < KPB * MT * MT; i += BS) {   // strided: 1600 > BS
        int kk = i / (MT * MT), rr = i - kk * (MT * MT);
        int rs = rr / MT, rt = rr - rs * MT;
        float v = C2g[i];
        s_C2sq[kk][rs][rt] = gl2 * v * v;
    }
    // iter-0 fold constants: A[k][s] = (tgl/170)*sum_t C2, B[k][s] = 0.1*gl2*sum_t C2^2
    if (tid < NTPL * MT) {
        int kk = tid / MT, s = tid - kk * MT;
        const float* cr = C2g + (size_t)kk * MT * MT + s * MT;
        float rs = 0.f, rq = 0.f;
        #pragma unroll
        for (int t = 0; t < MT; t++) { float c = cr[t]; rs += c; rq = fmaf(c, c, rq); }
        s_A[kk][s] = (tgl / 170.f) * rs;
        s_B[kk][s] = 0.1f * gl2 * rq;
    }
    __syncthreads();

    if (tid < NPB * MM * MM) {
        int node = tid / (MM * MM), rr = tid - node * (MM * MM);
        int pa = rr / MM, pb = rr - pa * MM;
        int vtgt = s_nbr[node][pb];
        const int* ar = s_adj[node * MM + pa];
        bool e = false;
        #pragma unroll
        for (int j = 0; j < DEG; j++) e = e | (ar[j] == vtgt);
        if (e) {
            atomicOr(&s_mask[node][pa], 1u << pb);
            atomicOr(&s_mask[node][pb], 1u << pa);
        }
    }
    __syncthreads();

    // ---- lane mapping: wave kw owns template kw; 3 groups/wave ----
    const int  kw    = tid >> 6;
    const int  ln    = tid & 63;
    const bool isR16 = (ln >= 48) && (ln < 51);
    const bool valid = (ln < 51);
    int g = isR16 ? (ln - 48) : (ln >> 4);
    if (g >= NPB) g = 0;
    const int a = isR16 ? 16 : (ln & 15);

    const int k_u = __builtin_amdgcn_readfirstlane(kw);
    const float* __restrict__ c2p = C2g + (size_t)k_u * MT * MT;

    const int vv = s_nbr[g][a];

    float Mc[MT];
    if (useG) {
        const float2* gp = reinterpret_cast<const float2*>(G + (size_t)vv * (NTPL * MT) + k_u * MT);
        #pragma unroll
        for (int j = 0; j < 5; j++) {
            float2 w = gp[j];
            Mc[2 * j] = w.x; Mc[2 * j + 1] = w.y;
        }
    } else {
        float dot[MT], sq2[MT];
        #pragma unroll
        for (int t = 0; t < MT; t++) { dot[t] = 0.f; sq2[t] = 0.f; }
        const float4* xr = reinterpret_cast<const float4*>(x + (size_t)vv * NF);
        const float4* fr = reinterpret_cast<const float4*>(F2g + (size_t)k_u * MT * NF);
        for (int f = 0; f < NF / 4; f++) {
            float4 xa = xr[f];
            #pragma unroll
            for (int t = 0; t < MT; t++) {
                float4 b = fr[t * (NF / 4) + f];
                dot[t] += xa.x * b.x + xa.y * b.y + xa.z * b.z + xa.w * b.w;
                sq2[t] += b.x * b.x + b.y * b.y + b.z * b.z + b.w * b.w;
            }
        }
        const float mcoefl = (1.f - alpha) * 10.f * LOG2E;
        #pragma unroll
        for (int t = 0; t < MT; t++) Mc[t] = mcoefl * (sq2[t] - 2.f * dot[t]);
    }

    unsigned mask = valid ? s_mask[g][a] : 0u;
    const int  pcnt = __popc(mask);
    const bool cmpl = pcnt > 8;
    unsigned   lmask = cmpl ? (~mask & 0x1FFFFu) : mask;
    if (!valid) lmask = 0u;
    const float sgn = cmpl ? -1.f : 1.f;
    const float P   = 1.f / 17.f;

    // ---- iter-0 analytic fold: lt_1[s] = pcnt*A[s] - B[s] - Mc[s] ----
    float lt[MT];
    {
        const float pcf = (float)pcnt;
        const float2* Ap = reinterpret_cast<const float2*>(&s_A[kw][0]);
        const float2* Bp = reinterpret_cast<const float2*>(&s_B[kw][0]);
        #pragma unroll
        for (int j = 0; j < 5; j++) {
            float2 av = Ap[j], bv = Bp[j];
            lt[2 * j]     = fmaf(pcf, av.x, -bv.x - Mc[2 * j]);
            lt[2 * j + 1] = fmaf(pcf, av.y, -bv.y - Mc[2 * j + 1]);
        }
    }

    float4* Trow = reinterpret_cast<float4*>(&s_T[kw][g][a][0]);
    float q[MT];

    for (int it = 1; it <= NITER; it++) {
        // thread-local softmax (log2 domain, native v_exp_f32 + v_rcp_f32)
        float mx = lt[0];
        #pragma unroll
        for (int t = 1; t < MT; t++) mx = fmaxf(mx, lt[t]);
        float e[MT], ss = 0.f;
        #pragma unroll
        for (int t = 0; t < MT; t++) { e[t] = fexp2(lt[t] - mx); ss += e[t]; }
        float sc = P * frcp(ss);
        #pragma unroll
        for (int t = 0; t < MT; t++) e[t] *= sc;

        __builtin_amdgcn_wave_barrier();
        if (valid) {
            Trow[0] = make_float4(e[0], e[1], e[2], e[3]);
            Trow[1] = make_float4(e[4], e[5], e[6], e[7]);
            reinterpret_cast<float2*>(Trow)[4] = make_float2(e[8], e[9]);
        }
        __builtin_amdgcn_wave_barrier();

        // q via DPP rotate-reduce over 16-lane row (all 16 lanes get the sum)
        #pragma unroll
        for (int t = 0; t < MT; t++) {
            float s = e[t];
            s = ror_add<0x121>(s);
            s = ror_add<0x122>(s);
            s = ror_add<0x124>(s);
            s = ror_add<0x128>(s);
            q[t] = s;
        }
        if (valid && a < 16) {   // add row 16 from LDS
            const float4* r16 = reinterpret_cast<const float4*>(&s_T[kw][g][16][0]);
            float4 ra = r16[0], rb = r16[1];
            float2 rc = reinterpret_cast<const float2*>(r16)[4];
            q[0] += ra.x; q[1] += ra.y; q[2] += ra.z; q[3] += ra.w;
            q[4] += rb.x; q[5] += rb.y; q[6] += rb.z; q[7] += rb.w;
            q[8] += rc.x; q[9] += rc.y;
        }
        if (valid && a == 0) {   // publish q (row-16 lanes + final output)
            float2* qp = reinterpret_cast<float2*>(&s_q[kw][g][0]);
            #pragma unroll
            for (int j = 0; j < 5; j++) qp[j] = make_float2(q[2 * j], q[2 * j + 1]);
        }
        __builtin_amdgcn_wave_barrier();
        if (isR16) {
            const float2* qp = reinterpret_cast<const float2*>(&s_q[kw][g][0]);
            #pragma unroll
            for (int j = 0; j < 5; j++) {
                float2 w = qp[j];
                q[2 * j] = w.x; q[2 * j + 1] = w.y;
            }
        }
        if (it == NITER) break;

        // cooperative cc[s] (C2sq pre-scaled by gcoef*log2e)
        if (valid && a < MT) {
            const float4* cr = reinterpret_cast<const float4*>(&s_C2sq[kw][a][0]);
            float4 ca = cr[0], cb = cr[1];
            float2 c2 = reinterpret_cast<const float2*>(cr)[4];
            float cc = q[0] * ca.x + q[1] * ca.y + q[2] * ca.z + q[3] * ca.w
                     + q[4] * cb.x + q[5] * cb.y + q[6] * cb.z + q[7] * cb.w
                     + q[8] * c2.x + q[9] * c2.y;
            s_cc[kw][g][a] = cc;
        }
        __builtin_amdgcn_wave_barrier();
        float ccr[MT];
        {
            const float4* cp = reinterpret_cast<const float4*>(&s_cc[kw][g][0]);
            float4 ca = cp[0], cb = cp[1];
            float2 c2 = reinterpret_cast<const float2*>(cp)[4];
            ccr[0] = ca.x; ccr[1] = ca.y; ccr[2] = ca.z; ccr[3] = ca.w;
            ccr[4] = cb.x; ccr[5] = cb.y; ccr[6] = cb.z; ccr[7] = cb.w;
            ccr[8] = c2.x; ccr[9] = c2.y;
        }

        // Y1 via bitmask (complement trick)
        float y1[MT];
        #pragma unroll
        for (int t = 0; t < MT; t++) y1[t] = cmpl ? q[t] : 0.f;
        unsigned mm = lmask;
        while (mm) {
            int b = __ffs(mm) - 1;
            mm &= mm - 1;
            const float4* rb4 = reinterpret_cast<const float4*>(&s_T[kw][g][b][0]);
            float4 ra = rb4[0], rb = rb4[1];
            float2 rc = reinterpret_cast<const float2*>(rb4)[4];
            y1[0] += sgn * ra.x; y1[1] += sgn * ra.y; y1[2] += sgn * ra.z; y1[3] += sgn * ra.w;
            y1[4] += sgn * rb.x; y1[5] += sgn * rb.y; y1[6] += sgn * rb.z; y1[7] += sgn * rb.w;
            y1[8] += sgn * rc.x; y1[9] += sgn * rc.y;
        }

        // y2 matvec (wave-uniform scalar C2) + log2-domain update
        #pragma unroll
        for (int s = 0; s < MT; s++) {
            float y2 = 0.f;
            #pragma unroll
            for (int t = 0; t < MT; t++) y2 = fmaf(y1[t], c2p[s * MT + t], y2);
            lt[s] += tgl * y2 - ccr[s] - Mc[s];
        }
    }

    if (valid && a < MT)
        out[(size_t)(nb + g) * (NTPL * MT) + k_u * MT + a] = s_q[kw][g][a];
}

extern "C" void kernel_launch(void* const* d_in, const int* in_sizes, int n_in,
                              void* d_out, int out_size, void* d_ws, size_t ws_size,
                              hipStream_t stream) {
    const float* x      = (const float*)d_in[0];
    const int*   eidx   = (const int*)d_in[1];
    const float* tmpl   = (const float*)d_in[2];
    const float* tmplf  = (const float*)d_in[3];
    const float* alpha0 = (const float*)d_in[4];
    float*       outp   = (float*)d_out;

    const int* dst = eidx + NN * DEG;
    float* G = (float*)d_ws;
    const size_t gbytes = (size_t)NN * NTPL * MT * sizeof(float);
    int useG = (ws_size >= gbytes) ? 1 : 0;

    if (useG)
        gcost_kernel<<<dim3(NN / GNV, 20), dim3(256), 0, stream>>>(x, tmplf, alpha0, G);

    srfgw_kernel<<<dim3(NN / NPB), dim3(BS), 0, stream>>>(
        x, dst, tmpl, tmplf, alpha0, G, useG, outp);
}

// Round 11
// 222.135 us; speedup vs baseline: 1.1304x; 1.1304x over previous
//
#include <hip/hip_runtime.h>

// LTFGW semi-relaxed FGW — round 11.
// srfgw change: DPP q-reduce (80 VALU instr/iter = 160 issue-cyc, the largest
//   removable VALU block at 85% VALUBusy) replaced by an LDS column sum on
//   lanes a<10 (17x stride-12 ds_read_b32 -> ds_read2 pairs, ~2-way alias =
//   free; 16 adds), q read back by all lanes as 2xb128+b64. Row-16 add, DPP
//   glue, isR16 readback, and the final s_q output bounce all die with it.
//   Net: VALU -148 cyc/wave-iter, DS ~31->~25 instr/wave-iter.
// gcost: round-10 v3 unchanged (half-wave per kt, register F2, DPP reduce).
// Everything else = round 9/10 (iter-0 fold, native exp2/rcp, log2 domain,
//   dual-atomicOr masks, scalar-C2 y2 matvec).

#define NN    6000
#define DEG   16
#define MM    17
#define NTPL  16
#define MT    10
#define NF    128
#define NITER 10
#define KPB   16
#define NPB   3
#define BS    1024
#define RS    12            // padded T row stride (floats)
#define LOG2E 1.44269504088896340736f

template<int C>
__device__ __forceinline__ float ror_add(float v) {
    int s = __builtin_amdgcn_update_dpp(0, __float_as_int(v), C, 0xf, 0xf, true);
    return v + __int_as_float(s);
}

__device__ __forceinline__ float fexp2(float x) { return __builtin_amdgcn_exp2f(x); }
__device__ __forceinline__ float frcp(float x)  { return __builtin_amdgcn_rcpf(x); }

// sum over 32 consecutive lanes (result in all 32)
__device__ __forceinline__ float reduce32(float v) {
    v = ror_add<0x121>(v);
    v = ror_add<0x122>(v);
    v = ror_add<0x124>(v);
    v = ror_add<0x128>(v);
    int s = __builtin_amdgcn_ds_swizzle(__float_as_int(v), 0x401F); // xor lane^16
    return v + __int_as_float(s);
}

// ---------------- gcost v3 (round-10 verbatim)
#define GNV 30
__global__ __launch_bounds__(256) void gcost_kernel(
    const float* __restrict__ x, const float* __restrict__ F2g,
    const float* __restrict__ alpha0, float* __restrict__ G)
{
    const int wv   = threadIdx.x >> 6;       // 0..3
    const int ln   = threadIdx.x & 63;
    const int half = ln >> 5;                // 0/1
    const int l32  = ln & 31;
    const int kt   = blockIdx.y * 8 + wv * 2 + half;   // grid.y=20 -> 0..159

    const float4 f2 = reinterpret_cast<const float4*>(F2g + (size_t)kt * NF)[l32];
    float sq = reduce32(f2.x * f2.x + f2.y * f2.y + f2.z * f2.z + f2.w * f2.w);

    const float alpha  = 1.f / (1.f + __expf(-alpha0[0]));
    const float mcoefl = (1.f - alpha) * 10.f * LOG2E;

    const int v0 = blockIdx.x * GNV;
    #pragma unroll 2
    for (int i = 0; i < GNV; i++) {
        const int v = v0 + i;
        float4 xv = reinterpret_cast<const float4*>(x + (size_t)v * NF)[l32];
        float d = xv.x * f2.x + xv.y * f2.y + xv.z * f2.z + xv.w * f2.w;
        d = reduce32(d);
        if (l32 == 0)
            G[(size_t)v * (NTPL * MT) + kt] = mcoefl * (sq - 2.f * d);
    }
}

// ---------------- main kernel
__global__ __launch_bounds__(BS, 4) void srfgw_kernel(
    const float* __restrict__ x,
    const int*   __restrict__ dst,
    const float* __restrict__ C2g,
    const float* __restrict__ F2g,
    const float* __restrict__ alpha0,
    const float* __restrict__ G,
    int useG,
    float*       __restrict__ out)
{
    const int nb  = blockIdx.x * NPB;
    const int tid = threadIdx.x;

    __shared__ __align__(16) float s_T[KPB][NPB][MM][RS];     // 39168 B
    __shared__ __align__(16) float s_C2sq[KPB][MT][RS];       // 7680 B
    __shared__ __align__(16) float s_q[KPB][NPB][RS];         // 2304 B
    __shared__ __align__(16) float s_cc[KPB][NPB][RS];        // 2304 B
    __shared__ __align__(16) float s_A[KPB][RS];              // 768 B (iter-0 fold)
    __shared__ __align__(16) float s_B[KPB][RS];              // 768 B
    __shared__ __align__(16) int   s_adj[NPB * MM][DEG];      // 3264 B
    __shared__ int      s_nbr[NPB][MM];
    __shared__ unsigned s_mask[NPB][MM];

    const float aval  = alpha0[0];
    const float alpha = 1.f / (1.f + __expf(-aval));
    const float gcoef = 2.f * alpha * 10.f;
    const float tgl   = 2.f * gcoef * LOG2E;
    const float gl2   = gcoef * LOG2E;

    if (tid < NPB * MM) {
        int node = tid / MM, a0 = tid - node * MM;
        s_nbr[node][a0]  = (a0 == 0) ? (nb + node) : dst[(size_t)(nb + node) * DEG + a0 - 1];
        s_mask[node][a0] = 0u;
    }
    __syncthreads();

    if (tid < NPB * MM * DEG) {
        int r = tid >> 4, j = tid & 15;
        int node = r / MM, a0 = r - node * MM;
        s_adj[r][j] = dst[(size_t)s_nbr[node][a0] * DEG + j];
    }
    for (int i = tid; i < KPB * MT * MT; i += BS) {   // strided: 1600 > BS
        int kk = i / (MT * MT), rr = i - kk * (MT * MT);
        int rs = rr / MT, rt = rr - rs * MT;
        float v = C2g[i];
        s_C2sq[kk][rs][rt] = gl2 * v * v;
    }
    // iter-0 fold constants: A[k][s] = (tgl/170)*sum_t C2, B[k][s] = 0.1*gl2*sum_t C2^2
    if (tid < NTPL * MT) {
        int kk = tid / MT, s = tid - kk * MT;
        const float* cr = C2g + (size_t)kk * MT * MT + s * MT;
        float rs = 0.f, rq = 0.f;
        #pragma unroll
        for (int t = 0; t < MT; t++) { float c = cr[t]; rs += c; rq = fmaf(c, c, rq); }
        s_A[kk][s] = (tgl / 170.f) * rs;
        s_B[kk][s] = 0.1f * gl2 * rq;
    }
    __syncthreads();

    if (tid < NPB * MM * MM) {
        int node = tid / (MM * MM), rr = tid - node * (MM * MM);
        int pa = rr / MM, pb = rr - pa * MM;
        int vtgt = s_nbr[node][pb];
        const int* ar = s_adj[node * MM + pa];
        bool e = false;
        #pragma unroll
        for (int j = 0; j < DEG; j++) e = e | (ar[j] == vtgt);
        if (e) {
            atomicOr(&s_mask[node][pa], 1u << pb);
            atomicOr(&s_mask[node][pb], 1u << pa);
        }
    }
    __syncthreads();

    // ---- lane mapping: wave kw owns template kw; 3 groups/wave ----
    const int  kw    = tid >> 6;
    const int  ln    = tid & 63;
    const bool isR16 = (ln >= 48) && (ln < 51);
    const bool valid = (ln < 51);
    int g = isR16 ? (ln - 48) : (ln >> 4);
    if (g >= NPB) g = 0;
    const int a = isR16 ? 16 : (ln & 15);

    const int k_u = __builtin_amdgcn_readfirstlane(kw);
    const float* __restrict__ c2p = C2g + (size_t)k_u * MT * MT;

    const int vv = s_nbr[g][a];

    float Mc[MT];
    if (useG) {
        const float2* gp = reinterpret_cast<const float2*>(G + (size_t)vv * (NTPL * MT) + k_u * MT);
        #pragma unroll
        for (int j = 0; j < 5; j++) {
            float2 w = gp[j];
            Mc[2 * j] = w.x; Mc[2 * j + 1] = w.y;
        }
    } else {
        float dot[MT], sq2[MT];
        #pragma unroll
        for (int t = 0; t < MT; t++) { dot[t] = 0.f; sq2[t] = 0.f; }
        const float4* xr = reinterpret_cast<const float4*>(x + (size_t)vv * NF);
        const float4* fr = reinterpret_cast<const float4*>(F2g + (size_t)k_u * MT * NF);
        for (int f = 0; f < NF / 4; f++) {
            float4 xa = xr[f];
            #pragma unroll
            for (int t = 0; t < MT; t++) {
                float4 b = fr[t * (NF / 4) + f];
                dot[t] += xa.x * b.x + xa.y * b.y + xa.z * b.z + xa.w * b.w;
                sq2[t] += b.x * b.x + b.y * b.y + b.z * b.z + b.w * b.w;
            }
        }
        const float mcoefl = (1.f - alpha) * 10.f * LOG2E;
        #pragma unroll
        for (int t = 0; t < MT; t++) Mc[t] = mcoefl * (sq2[t] - 2.f * dot[t]);
    }

    unsigned mask = valid ? s_mask[g][a] : 0u;
    const int  pcnt = __popc(mask);
    const bool cmpl = pcnt > 8;
    unsigned   lmask = cmpl ? (~mask & 0x1FFFFu) : mask;
    if (!valid) lmask = 0u;
    const float sgn = cmpl ? -1.f : 1.f;
    const float P   = 1.f / 17.f;

    // ---- iter-0 analytic fold: lt_1[s] = pcnt*A[s] - B[s] - Mc[s] ----
    float lt[MT];
    {
        const float pcf = (float)pcnt;
        const float2* Ap = reinterpret_cast<const float2*>(&s_A[kw][0]);
        const float2* Bp = reinterpret_cast<const float2*>(&s_B[kw][0]);
        #pragma unroll
        for (int j = 0; j < 5; j++) {
            float2 av = Ap[j], bv = Bp[j];
            lt[2 * j]     = fmaf(pcf, av.x, -bv.x - Mc[2 * j]);
            lt[2 * j + 1] = fmaf(pcf, av.y, -bv.y - Mc[2 * j + 1]);
        }
    }

    float4* Trow = reinterpret_cast<float4*>(&s_T[kw][g][a][0]);
    const bool doCol = valid && (a < MT);
    float qa = 0.f;   // own-column sum (final-iter output comes from here)

    for (int it = 1; it <= NITER; it++) {
        // thread-local softmax (log2 domain, native v_exp_f32 + v_rcp_f32)
        float mx = lt[0];
        #pragma unroll
        for (int t = 1; t < MT; t++) mx = fmaxf(mx, lt[t]);
        float e[MT], ss = 0.f;
        #pragma unroll
        for (int t = 0; t < MT; t++) { e[t] = fexp2(lt[t] - mx); ss += e[t]; }
        float sc = P * frcp(ss);
        #pragma unroll
        for (int t = 0; t < MT; t++) e[t] *= sc;

        __builtin_amdgcn_wave_barrier();   // prior iter's s_T readers ordered first
        if (valid) {
            Trow[0] = make_float4(e[0], e[1], e[2], e[3]);
            Trow[1] = make_float4(e[4], e[5], e[6], e[7]);
            reinterpret_cast<float2*>(Trow)[4] = make_float2(e[8], e[9]);
        }
        __builtin_amdgcn_wave_barrier();

        // q via LDS column sum on lanes a<10 (17 stride-12 reads -> ds_read2
        // pairs, ~2-way alias = free; DS pipe, replacing 80 DPP VALU instr)
        if (doCol) {
            const float* colp = &s_T[kw][g][0][a];
            float s0 = 0.f;
            #pragma unroll
            for (int m = 0; m < MM; m++) s0 += colp[m * RS];
            qa = s0;
            s_q[kw][g][a] = s0;
        }
        __builtin_amdgcn_wave_barrier();
        if (it == NITER) break;

        // all lanes read q back (2xb128 + b64; same-address = LDS broadcast)
        float q[MT];
        {
            const float4* qp4 = reinterpret_cast<const float4*>(&s_q[kw][g][0]);
            float4 qx = qp4[0], qy = qp4[1];
            float2 qz = reinterpret_cast<const float2*>(qp4)[4];
            q[0] = qx.x; q[1] = qx.y; q[2] = qx.z; q[3] = qx.w;
            q[4] = qy.x; q[5] = qy.y; q[6] = qy.z; q[7] = qy.w;
            q[8] = qz.x; q[9] = qz.y;
        }

        // cooperative cc[s] (C2sq pre-scaled by gcoef*log2e)
        if (doCol) {
            const float4* cr = reinterpret_cast<const float4*>(&s_C2sq[kw][a][0]);
            float4 ca = cr[0], cb = cr[1];
            float2 c2 = reinterpret_cast<const float2*>(cr)[4];
            float cc = q[0] * ca.x + q[1] * ca.y + q[2] * ca.z + q[3] * ca.w
                     + q[4] * cb.x + q[5] * cb.y + q[6] * cb.z + q[7] * cb.w
                     + q[8] * c2.x + q[9] * c2.y;
            s_cc[kw][g][a] = cc;
        }
        __builtin_amdgcn_wave_barrier();
        float ccr[MT];
        {
            const float4* cp = reinterpret_cast<const float4*>(&s_cc[kw][g][0]);
            float4 ca = cp[0], cb = cp[1];
            float2 c2 = reinterpret_cast<const float2*>(cp)[4];
            ccr[0] = ca.x; ccr[1] = ca.y; ccr[2] = ca.z; ccr[3] = ca.w;
            ccr[4] = cb.x; ccr[5] = cb.y; ccr[6] = cb.z; ccr[7] = cb.w;
            ccr[8] = c2.x; ccr[9] = c2.y;
        }

        // Y1 via bitmask (complement trick)
        float y1[MT];
        #pragma unroll
        for (int t = 0; t < MT; t++) y1[t] = cmpl ? q[t] : 0.f;
        unsigned mm = lmask;
        while (mm) {
            int b = __ffs(mm) - 1;
            mm &= mm - 1;
            const float4* rb4 = reinterpret_cast<const float4*>(&s_T[kw][g][b][0]);
            float4 ra = rb4[0], rb = rb4[1];
            float2 rc = reinterpret_cast<const float2*>(rb4)[4];
            y1[0] += sgn * ra.x; y1[1] += sgn * ra.y; y1[2] += sgn * ra.z; y1[3] += sgn * ra.w;
            y1[4] += sgn * rb.x; y1[5] += sgn * rb.y; y1[6] += sgn * rb.z; y1[7] += sgn * rb.w;
            y1[8] += sgn * rc.x; y1[9] += sgn * rc.y;
        }

        // y2 matvec (wave-uniform scalar C2) + log2-domain update
        #pragma unroll
        for (int s = 0; s < MT; s++) {
            float y2 = 0.f;
            #pragma unroll
            for (int t = 0; t < MT; t++) y2 = fmaf(y1[t], c2p[s * MT + t], y2);
            lt[s] += tgl * y2 - ccr[s] - Mc[s];
        }
    }

    if (doCol)
        out[(size_t)(nb + g) * (NTPL * MT) + k_u * MT + a] = qa;
}

extern "C" void kernel_launch(void* const* d_in, const int* in_sizes, int n_in,
                              void* d_out, int out_size, void* d_ws, size_t ws_size,
                              hipStream_t stream) {
    const float* x      = (const float*)d_in[0];
    const int*   eidx   = (const int*)d_in[1];
    const float* tmpl   = (const float*)d_in[2];
    const float* tmplf  = (const float*)d_in[3];
    const float* alpha0 = (const float*)d_in[4];
    float*       outp   = (float*)d_out;

    const int* dst = eidx + NN * DEG;
    float* G = (float*)d_ws;
    const size_t gbytes = (size_t)NN * NTPL * MT * sizeof(float);
    int useG = (ws_size >= gbytes) ? 1 : 0;

    if (useG)
        gcost_kernel<<<dim3(NN / GNV, 20), dim3(256), 0, stream>>>(x, tmplf, alpha0, G);

    srfgw_kernel<<<dim3(NN / NPB), dim3(BS), 0, stream>>>(
        x, dst, tmpl, tmplf, alpha0, G, useG, outp);
}

// Round 12
// 217.549 us; speedup vs baseline: 1.1542x; 1.0211x over previous
//
#include <hip/hip_runtime.h>

// LTFGW semi-relaxed FGW — round 12: residency, not instructions.
// Round-11: VALUBusy 83%, Occupancy 44% (~1x1024-thr block/CU; 56.8KB LDS
//   blocks a 2nd). The un-hidden part is the per-iter DS chain (T-write ->
//   colsum -> q -> cc -> ccr). Fix: KPB 16->8, BS 1024->512, grid.y=2 ->
//   LDS ~30KB -> 4 blocks/CU (32 waves, thread-capped), 2.3x wave residency.
// Guard audit (round-4 lesson): adjacency(816) & mask(867) > BS=512 ->
//   strided; C2sq / iter-0 A,B staging now offset by kb.
// srfgw loop body + gcost v3: round-11 verbatim (LDS colsum q, iter-0 fold,
//   native exp2/rcp, log2 domain, scalar-C2 y2 matvec).

#define NN    6000
#define DEG   16
#define MM    17
#define NTPL  16
#define MT    10
#define NF    128
#define NITER 10
#define KPB   8
#define NPB   3
#define BS    512
#define RS    12            // padded T row stride (floats)
#define LOG2E 1.44269504088896340736f

template<int C>
__device__ __forceinline__ float ror_add(float v) {
    int s = __builtin_amdgcn_update_dpp(0, __float_as_int(v), C, 0xf, 0xf, true);
    return v + __int_as_float(s);
}

__device__ __forceinline__ float fexp2(float x) { return __builtin_amdgcn_exp2f(x); }
__device__ __forceinline__ float frcp(float x)  { return __builtin_amdgcn_rcpf(x); }

// sum over 32 consecutive lanes (result in all 32)
__device__ __forceinline__ float reduce32(float v) {
    v = ror_add<0x121>(v);
    v = ror_add<0x122>(v);
    v = ror_add<0x124>(v);
    v = ror_add<0x128>(v);
    int s = __builtin_amdgcn_ds_swizzle(__float_as_int(v), 0x401F); // xor lane^16
    return v + __int_as_float(s);
}

// ---------------- gcost v3 (round-10 verbatim)
#define GNV 30
__global__ __launch_bounds__(256) void gcost_kernel(
    const float* __restrict__ x, const float* __restrict__ F2g,
    const float* __restrict__ alpha0, float* __restrict__ G)
{
    const int wv   = threadIdx.x >> 6;       // 0..3
    const int ln   = threadIdx.x & 63;
    const int half = ln >> 5;                // 0/1
    const int l32  = ln & 31;
    const int kt   = blockIdx.y * 8 + wv * 2 + half;   // grid.y=20 -> 0..159

    const float4 f2 = reinterpret_cast<const float4*>(F2g + (size_t)kt * NF)[l32];
    float sq = reduce32(f2.x * f2.x + f2.y * f2.y + f2.z * f2.z + f2.w * f2.w);

    const float alpha  = 1.f / (1.f + __expf(-alpha0[0]));
    const float mcoefl = (1.f - alpha) * 10.f * LOG2E;

    const int v0 = blockIdx.x * GNV;
    #pragma unroll 2
    for (int i = 0; i < GNV; i++) {
        const int v = v0 + i;
        float4 xv = reinterpret_cast<const float4*>(x + (size_t)v * NF)[l32];
        float d = xv.x * f2.x + xv.y * f2.y + xv.z * f2.z + xv.w * f2.w;
        d = reduce32(d);
        if (l32 == 0)
            G[(size_t)v * (NTPL * MT) + kt] = mcoefl * (sq - 2.f * d);
    }
}

// ---------------- main kernel
__global__ __launch_bounds__(BS, 4) void srfgw_kernel(
    const float* __restrict__ x,
    const int*   __restrict__ dst,
    const float* __restrict__ C2g,
    const float* __restrict__ F2g,
    const float* __restrict__ alpha0,
    const float* __restrict__ G,
    int useG,
    float*       __restrict__ out)
{
    const int nb  = blockIdx.x * NPB;
    const int kb  = blockIdx.y * KPB;
    const int tid = threadIdx.x;

    __shared__ __align__(16) float s_T[KPB][NPB][MM][RS];     // 19584 B
    __shared__ __align__(16) float s_C2sq[KPB][MT][RS];       // 3840 B
    __shared__ __align__(16) float s_q[KPB][NPB][RS];         // 1152 B
    __shared__ __align__(16) float s_cc[KPB][NPB][RS];        // 1152 B
    __shared__ __align__(16) float s_A[KPB][RS];              // 384 B (iter-0 fold)
    __shared__ __align__(16) float s_B[KPB][RS];              // 384 B
    __shared__ __align__(16) int   s_adj[NPB * MM][DEG];      // 3264 B
    __shared__ int      s_nbr[NPB][MM];
    __shared__ unsigned s_mask[NPB][MM];

    const float aval  = alpha0[0];
    const float alpha = 1.f / (1.f + __expf(-aval));
    const float gcoef = 2.f * alpha * 10.f;
    const float tgl   = 2.f * gcoef * LOG2E;
    const float gl2   = gcoef * LOG2E;

    if (tid < NPB * MM) {
        int node = tid / MM, a0 = tid - node * MM;
        s_nbr[node][a0]  = (a0 == 0) ? (nb + node) : dst[(size_t)(nb + node) * DEG + a0 - 1];
        s_mask[node][a0] = 0u;
    }
    __syncthreads();

    // adjacency rows (816 > BS -> strided)
    for (int i = tid; i < NPB * MM * DEG; i += BS) {
        int r = i >> 4, j = i & 15;
        int node = r / MM, a0 = r - node * MM;
        s_adj[r][j] = dst[(size_t)s_nbr[node][a0] * DEG + j];
    }
    // C2^2 * gcoef*log2e for THIS k-half (800 > BS -> strided; kb offset!)
    for (int i = tid; i < KPB * MT * MT; i += BS) {
        int kk = i / (MT * MT), rr = i - kk * (MT * MT);
        int rs = rr / MT, rt = rr - rs * MT;
        float v = C2g[(size_t)kb * MT * MT + i];
        s_C2sq[kk][rs][rt] = gl2 * v * v;
    }
    // iter-0 fold constants for this k-half (80 <= BS)
    if (tid < KPB * MT) {
        int kk = tid / MT, s = tid - kk * MT;
        const float* cr = C2g + (size_t)(kb + kk) * MT * MT + s * MT;
        float rs = 0.f, rq = 0.f;
        #pragma unroll
        for (int t = 0; t < MT; t++) { float c = cr[t]; rs += c; rq = fmaf(c, c, rq); }
        s_A[kk][s] = (tgl / 170.f) * rs;
        s_B[kk][s] = 0.1f * gl2 * rq;
    }
    __syncthreads();

    // masks (867 > BS -> strided)
    for (int i = tid; i < NPB * MM * MM; i += BS) {
        int node = i / (MM * MM), rr = i - node * (MM * MM);
        int pa = rr / MM, pb = rr - pa * MM;
        int vtgt = s_nbr[node][pb];
        const int* ar = s_adj[node * MM + pa];
        bool e = false;
        #pragma unroll
        for (int j = 0; j < DEG; j++) e = e | (ar[j] == vtgt);
        if (e) {
            atomicOr(&s_mask[node][pa], 1u << pb);
            atomicOr(&s_mask[node][pb], 1u << pa);
        }
    }
    __syncthreads();

    // ---- lane mapping: wave kw owns template kb+kw; 3 groups/wave ----
    const int  kw    = tid >> 6;           // 0..7
    const int  ln    = tid & 63;
    const bool isR16 = (ln >= 48) && (ln < 51);
    const bool valid = (ln < 51);
    int g = isR16 ? (ln - 48) : (ln >> 4);
    if (g >= NPB) g = 0;
    const int a = isR16 ? 16 : (ln & 15);

    const int k_u = __builtin_amdgcn_readfirstlane(kb + kw);
    const float* __restrict__ c2p = C2g + (size_t)k_u * MT * MT;

    const int vv = s_nbr[g][a];

    float Mc[MT];
    if (useG) {
        const float2* gp = reinterpret_cast<const float2*>(G + (size_t)vv * (NTPL * MT) + k_u * MT);
        #pragma unroll
        for (int j = 0; j < 5; j++) {
            float2 w = gp[j];
            Mc[2 * j] = w.x; Mc[2 * j + 1] = w.y;
        }
    } else {
        float dot[MT], sq2[MT];
        #pragma unroll
        for (int t = 0; t < MT; t++) { dot[t] = 0.f; sq2[t] = 0.f; }
        const float4* xr = reinterpret_cast<const float4*>(x + (size_t)vv * NF);
        const float4* fr = reinterpret_cast<const float4*>(F2g + (size_t)k_u * MT * NF);
        for (int f = 0; f < NF / 4; f++) {
            float4 xa = xr[f];
            #pragma unroll
            for (int t = 0; t < MT; t++) {
                float4 b = fr[t * (NF / 4) + f];
                dot[t] += xa.x * b.x + xa.y * b.y + xa.z * b.z + xa.w * b.w;
                sq2[t] += b.x * b.x + b.y * b.y + b.z * b.z + b.w * b.w;
            }
        }
        const float mcoefl = (1.f - alpha) * 10.f * LOG2E;
        #pragma unroll
        for (int t = 0; t < MT; t++) Mc[t] = mcoefl * (sq2[t] - 2.f * dot[t]);
    }

    unsigned mask = valid ? s_mask[g][a] : 0u;
    const int  pcnt = __popc(mask);
    const bool cmpl = pcnt > 8;
    unsigned   lmask = cmpl ? (~mask & 0x1FFFFu) : mask;
    if (!valid) lmask = 0u;
    const float sgn = cmpl ? -1.f : 1.f;
    const float P   = 1.f / 17.f;

    // ---- iter-0 analytic fold: lt_1[s] = pcnt*A[s] - B[s] - Mc[s] ----
    float lt[MT];
    {
        const float pcf = (float)pcnt;
        const float2* Ap = reinterpret_cast<const float2*>(&s_A[kw][0]);
        const float2* Bp = reinterpret_cast<const float2*>(&s_B[kw][0]);
        #pragma unroll
        for (int j = 0; j < 5; j++) {
            float2 av = Ap[j], bv = Bp[j];
            lt[2 * j]     = fmaf(pcf, av.x, -bv.x - Mc[2 * j]);
            lt[2 * j + 1] = fmaf(pcf, av.y, -bv.y - Mc[2 * j + 1]);
        }
    }

    float4* Trow = reinterpret_cast<float4*>(&s_T[kw][g][a][0]);
    const bool doCol = valid && (a < MT);
    float qa = 0.f;   // own-column sum (final-iter output comes from here)

    for (int it = 1; it <= NITER; it++) {
        // thread-local softmax (log2 domain, native v_exp_f32 + v_rcp_f32)
        float mx = lt[0];
        #pragma unroll
        for (int t = 1; t < MT; t++) mx = fmaxf(mx, lt[t]);
        float e[MT], ss = 0.f;
        #pragma unroll
        for (int t = 0; t < MT; t++) { e[t] = fexp2(lt[t] - mx); ss += e[t]; }
        float sc = P * frcp(ss);
        #pragma unroll
        for (int t = 0; t < MT; t++) e[t] *= sc;

        __builtin_amdgcn_wave_barrier();   // prior iter's s_T readers ordered first
        if (valid) {
            Trow[0] = make_float4(e[0], e[1], e[2], e[3]);
            Trow[1] = make_float4(e[4], e[5], e[6], e[7]);
            reinterpret_cast<float2*>(Trow)[4] = make_float2(e[8], e[9]);
        }
        __builtin_amdgcn_wave_barrier();

        // q via LDS column sum on lanes a<10 (DS pipe)
        if (doCol) {
            const float* colp = &s_T[kw][g][0][a];
            float s0 = 0.f;
            #pragma unroll
            for (int m = 0; m < MM; m++) s0 += colp[m * RS];
            qa = s0;
            s_q[kw][g][a] = s0;
        }
        __builtin_amdgcn_wave_barrier();
        if (it == NITER) break;

        // all lanes read q back (2xb128 + b64; same-address = LDS broadcast)
        float q[MT];
        {
            const float4* qp4 = reinterpret_cast<const float4*>(&s_q[kw][g][0]);
            float4 qx = qp4[0], qy = qp4[1];
            float2 qz = reinterpret_cast<const float2*>(qp4)[4];
            q[0] = qx.x; q[1] = qx.y; q[2] = qx.z; q[3] = qx.w;
            q[4] = qy.x; q[5] = qy.y; q[6] = qy.z; q[7] = qy.w;
            q[8] = qz.x; q[9] = qz.y;
        }

        // cooperative cc[s] (C2sq pre-scaled by gcoef*log2e)
        if (doCol) {
            const float4* cr = reinterpret_cast<const float4*>(&s_C2sq[kw][a][0]);
            float4 ca = cr[0], cb = cr[1];
            float2 c2 = reinterpret_cast<const float2*>(cr)[4];
            float cc = q[0] * ca.x + q[1] * ca.y + q[2] * ca.z + q[3] * ca.w
                     + q[4] * cb.x + q[5] * cb.y + q[6] * cb.z + q[7] * cb.w
                     + q[8] * c2.x + q[9] * c2.y;
            s_cc[kw][g][a] = cc;
        }
        __builtin_amdgcn_wave_barrier();
        float ccr[MT];
        {
            const float4* cp = reinterpret_cast<const float4*>(&s_cc[kw][g][0]);
            float4 ca = cp[0], cb = cp[1];
            float2 c2 = reinterpret_cast<const float2*>(cp)[4];
            ccr[0] = ca.x; ccr[1] = ca.y; ccr[2] = ca.z; ccr[3] = ca.w;
            ccr[4] = cb.x; ccr[5] = cb.y; ccr[6] = cb.z; ccr[7] = cb.w;
            ccr[8] = c2.x; ccr[9] = c2.y;
        }

        // Y1 via bitmask (complement trick)
        float y1[MT];
        #pragma unroll
        for (int t = 0; t < MT; t++) y1[t] = cmpl ? q[t] : 0.f;
        unsigned mm = lmask;
        while (mm) {
            int b = __ffs(mm) - 1;
            mm &= mm - 1;
            const float4* rb4 = reinterpret_cast<const float4*>(&s_T[kw][g][b][0]);
            float4 ra = rb4[0], rb = rb4[1];
            float2 rc = reinterpret_cast<const float2*>(rb4)[4];
            y1[0] += sgn * ra.x; y1[1] += sgn * ra.y; y1[2] += sgn * ra.z; y1[3] += sgn * ra.w;
            y1[4] += sgn * rb.x; y1[5] += sgn * rb.y; y1[6] += sgn * rb.z; y1[7] += sgn * rb.w;
            y1[8] += sgn * rc.x; y1[9] += sgn * rc.y;
        }

        // y2 matvec (wave-uniform scalar C2) + log2-domain update
        #pragma unroll
        for (int s = 0; s < MT; s++) {
            float y2 = 0.f;
            #pragma unroll
            for (int t = 0; t < MT; t++) y2 = fmaf(y1[t], c2p[s * MT + t], y2);
            lt[s] += tgl * y2 - ccr[s] - Mc[s];
        }
    }

    if (doCol)
        out[(size_t)(nb + g) * (NTPL * MT) + k_u * MT + a] = qa;
}

extern "C" void kernel_launch(void* const* d_in, const int* in_sizes, int n_in,
                              void* d_out, int out_size, void* d_ws, size_t ws_size,
                              hipStream_t stream) {
    const float* x      = (const float*)d_in[0];
    const int*   eidx   = (const int*)d_in[1];
    const float* tmpl   = (const float*)d_in[2];
    const float* tmplf  = (const float*)d_in[3];
    const float* alpha0 = (const float*)d_in[4];
    float*       outp   = (float*)d_out;

    const int* dst = eidx + NN * DEG;
    float* G = (float*)d_ws;
    const size_t gbytes = (size_t)NN * NTPL * MT * sizeof(float);
    int useG = (ws_size >= gbytes) ? 1 : 0;

    if (useG)
        gcost_kernel<<<dim3(NN / GNV, 20), dim3(256), 0, stream>>>(x, tmplf, alpha0, G);

    srfgw_kernel<<<dim3(NN / NPB, NTPL / KPB), dim3(BS), 0, stream>>>(
        x, dst, tmpl, tmplf, alpha0, G, useG, outp);
}

// Round 13
// 208.287 us; speedup vs baseline: 1.2056x; 1.0445x over previous
//
#include <hip/hip_runtime.h>

// LTFGW semi-relaxed FGW — round 13: lane packing 80% -> 93%.
// Round-12: VALUBusy 87% -> VALU-issue bound; 51/64 active rows per wave is
//   a 20% tax. Since round-11 the q-reduce is LDS-based (lane-agnostic), so
//   rows need not be wave-contiguous — only k must stay wave-uniform for the
//   scalar-C2 matvec. New shape: block 512 = 4 k x 7 nodes; per k, 119 rows
//   flat-packed in 128 lanes (93%), groups may straddle the k-pair's 2 waves.
//   wave_barrier -> 3x __syncthreads per iter (T -> colsum -> cc). Update
//   split (lt += tgl*y2 - Mc pre-barrier; lt -= ccr post) keeps regs flat.
// Guards (round-4 lesson): adj 1904 & masks 2023 > BS=512 -> strided;
//   7 does not divide 6000 -> staging clamp + output guard.
// gcost v3 + iter-0 fold + native exp2/rcp + log2 domain: unchanged.

#define NN    6000
#define DEG   16
#define MM    17
#define NTPL  16
#define MT    10
#define NF    128
#define NITER 10
#define KPB   4
#define NPB   7
#define BS    512
#define RS    12            // padded T row stride (floats)
#define LOG2E 1.44269504088896340736f

template<int C>
__device__ __forceinline__ float ror_add(float v) {
    int s = __builtin_amdgcn_update_dpp(0, __float_as_int(v), C, 0xf, 0xf, true);
    return v + __int_as_float(s);
}

__device__ __forceinline__ float fexp2(float x) { return __builtin_amdgcn_exp2f(x); }
__device__ __forceinline__ float frcp(float x)  { return __builtin_amdgcn_rcpf(x); }

__device__ __forceinline__ float reduce32(float v) {
    v = ror_add<0x121>(v);
    v = ror_add<0x122>(v);
    v = ror_add<0x124>(v);
    v = ror_add<0x128>(v);
    int s = __builtin_amdgcn_ds_swizzle(__float_as_int(v), 0x401F); // xor lane^16
    return v + __int_as_float(s);
}

// ---------------- gcost v3 (round-10 verbatim)
#define GNV 30
__global__ __launch_bounds__(256) void gcost_kernel(
    const float* __restrict__ x, const float* __restrict__ F2g,
    const float* __restrict__ alpha0, float* __restrict__ G)
{
    const int wv   = threadIdx.x >> 6;
    const int ln   = threadIdx.x & 63;
    const int half = ln >> 5;
    const int l32  = ln & 31;
    const int kt   = blockIdx.y * 8 + wv * 2 + half;

    const float4 f2 = reinterpret_cast<const float4*>(F2g + (size_t)kt * NF)[l32];
    float sq = reduce32(f2.x * f2.x + f2.y * f2.y + f2.z * f2.z + f2.w * f2.w);

    const float alpha  = 1.f / (1.f + __expf(-alpha0[0]));
    const float mcoefl = (1.f - alpha) * 10.f * LOG2E;

    const int v0 = blockIdx.x * GNV;
    #pragma unroll 2
    for (int i = 0; i < GNV; i++) {
        const int v = v0 + i;
        float4 xv = reinterpret_cast<const float4*>(x + (size_t)v * NF)[l32];
        float d = xv.x * f2.x + xv.y * f2.y + xv.z * f2.z + xv.w * f2.w;
        d = reduce32(d);
        if (l32 == 0)
            G[(size_t)v * (NTPL * MT) + kt] = mcoefl * (sq - 2.f * d);
    }
}

// ---------------- main kernel
__global__ __launch_bounds__(BS, 4) void srfgw_kernel(
    const float* __restrict__ x,
    const int*   __restrict__ dst,
    const float* __restrict__ C2g,
    const float* __restrict__ F2g,
    const float* __restrict__ alpha0,
    const float* __restrict__ G,
    int useG,
    float*       __restrict__ out)
{
    const int nb  = blockIdx.x * NPB;
    const int kb  = blockIdx.y * KPB;
    const int tid = threadIdx.x;

    __shared__ __align__(16) float s_T[KPB][NPB][MM][RS];     // 22848 B
    __shared__ __align__(16) float s_C2sq[KPB][MT][RS];       // 1920 B
    __shared__ __align__(16) float s_q[KPB][NPB][RS];         // 1344 B
    __shared__ __align__(16) float s_cc[KPB][NPB][RS];        // 1344 B
    __shared__ __align__(16) float s_A[KPB][RS];              // 192 B
    __shared__ __align__(16) float s_B[KPB][RS];              // 192 B
    __shared__ __align__(16) int   s_adj[NPB * MM][DEG];      // 7616 B
    __shared__ int      s_nbr[NPB][MM];
    __shared__ unsigned s_mask[NPB][MM];

    const float aval  = alpha0[0];
    const float alpha = 1.f / (1.f + __expf(-aval));
    const float gcoef = 2.f * alpha * 10.f;
    const float tgl   = 2.f * gcoef * LOG2E;
    const float gl2   = gcoef * LOG2E;

    // nbr (119 <= BS); node clamp: 7 does not divide 6000
    if (tid < NPB * MM) {
        int node = tid / MM, a0 = tid - node * MM;
        int nd  = nb + node;
        int ndc = nd < NN ? nd : NN - 1;
        s_nbr[node][a0]  = (a0 == 0) ? ndc : dst[(size_t)ndc * DEG + a0 - 1];
        s_mask[node][a0] = 0u;
    }
    __syncthreads();

    // adjacency rows (1904 > BS -> strided)
    for (int i = tid; i < NPB * MM * DEG; i += BS) {
        int r = i >> 4, j = i & 15;
        int node = r / MM, a0 = r - node * MM;
        s_adj[r][j] = dst[(size_t)s_nbr[node][a0] * DEG + j];
    }
    // C2sq (400, strided for safety; kb offset)
    for (int i = tid; i < KPB * MT * MT; i += BS) {
        int kk = i / (MT * MT), rr = i - kk * (MT * MT);
        int rs = rr / MT, rt = rr - rs * MT;
        float v = C2g[(size_t)kb * MT * MT + i];
        s_C2sq[kk][rs][rt] = gl2 * v * v;
    }
    // iter-0 fold constants (40 <= BS)
    if (tid < KPB * MT) {
        int kk = tid / MT, s = tid - kk * MT;
        const float* cr = C2g + (size_t)(kb + kk) * MT * MT + s * MT;
        float rs = 0.f, rq = 0.f;
        #pragma unroll
        for (int t = 0; t < MT; t++) { float c = cr[t]; rs += c; rq = fmaf(c, c, rq); }
        s_A[kk][s] = (tgl / 170.f) * rs;
        s_B[kk][s] = 0.1f * gl2 * rq;
    }
    __syncthreads();

    // masks (2023 > BS -> strided), dual atomicOr symmetrization
    for (int i = tid; i < NPB * MM * MM; i += BS) {
        int node = i / (MM * MM), rr = i - node * (MM * MM);
        int pa = rr / MM, pb = rr - pa * MM;
        int vtgt = s_nbr[node][pb];
        const int* ar = s_adj[node * MM + pa];
        bool e = false;
        #pragma unroll
        for (int j = 0; j < DEG; j++) e = e | (ar[j] == vtgt);
        if (e) {
            atomicOr(&s_mask[node][pa], 1u << pb);
            atomicOr(&s_mask[node][pb], 1u << pa);
        }
    }
    __syncthreads();

    // ---- row mapping: kh = tid>>7 (wave-uniform, 2 waves per k);
    //      rows flat-packed 119/128 lanes, groups may straddle the 2 waves ----
    const int  kh     = tid >> 7;              // 0..3
    const int  L      = tid & 127;
    const bool rvalid = L < NPB * MM;          // 119
    int gR = L / MM;
    int aR = L - gR * MM;
    if (!rvalid) { gR = 0; aR = 0; }

    const int k_u = __builtin_amdgcn_readfirstlane(kb + kh);
    const float* __restrict__ c2p = C2g + (size_t)k_u * MT * MT;

    const int vv = s_nbr[gR][aR];

    float Mc[MT];
    if (useG) {
        const float2* gp = reinterpret_cast<const float2*>(G + (size_t)vv * (NTPL * MT) + k_u * MT);
        #pragma unroll
        for (int j = 0; j < 5; j++) {
            float2 w = gp[j];
            Mc[2 * j] = w.x; Mc[2 * j + 1] = w.y;
        }
    } else {
        float dot[MT], sq2[MT];
        #pragma unroll
        for (int t = 0; t < MT; t++) { dot[t] = 0.f; sq2[t] = 0.f; }
        const float4* xr = reinterpret_cast<const float4*>(x + (size_t)vv * NF);
        const float4* fr = reinterpret_cast<const float4*>(F2g + (size_t)k_u * MT * NF);
        for (int f = 0; f < NF / 4; f++) {
            float4 xa = xr[f];
            #pragma unroll
            for (int t = 0; t < MT; t++) {
                float4 b = fr[t * (NF / 4) + f];
                dot[t] += xa.x * b.x + xa.y * b.y + xa.z * b.z + xa.w * b.w;
                sq2[t] += b.x * b.x + b.y * b.y + b.z * b.z + b.w * b.w;
            }
        }
        const float mcoefl = (1.f - alpha) * 10.f * LOG2E;
        #pragma unroll
        for (int t = 0; t < MT; t++) Mc[t] = mcoefl * (sq2[t] - 2.f * dot[t]);
    }

    unsigned mask = rvalid ? s_mask[gR][aR] : 0u;
    const int  pcnt = __popc(mask);
    const bool cmpl = pcnt > 8;
    unsigned   lmask = cmpl ? (~mask & 0x1FFFFu) : mask;
    if (!rvalid) lmask = 0u;
    const float sgn = cmpl ? -1.f : 1.f;
    const float P   = 1.f / 17.f;

    // ---- iter-0 analytic fold ----
    float lt[MT];
    {
        const float pcf = (float)pcnt;
        const float2* Ap = reinterpret_cast<const float2*>(&s_A[kh][0]);
        const float2* Bp = reinterpret_cast<const float2*>(&s_B[kh][0]);
        #pragma unroll
        for (int j = 0; j < 5; j++) {
            float2 av = Ap[j], bv = Bp[j];
            lt[2 * j]     = fmaf(pcf, av.x, -bv.x - Mc[2 * j]);
            lt[2 * j + 1] = fmaf(pcf, av.y, -bv.y - Mc[2 * j + 1]);
        }
    }

    // ---- colsum/cc mapping: tid < 280 -> (ck, cn, ct) ----
    const bool cvalid = tid < KPB * NPB * MT;  // 280
    int ck = 0, cn = 0, ct = 0;
    if (cvalid) {
        ck = tid / (NPB * MT);
        int rem = tid - ck * (NPB * MT);
        cn = rem / MT;
        ct = rem - cn * MT;
    }
    float qa = 0.f;

    float4* Trow = reinterpret_cast<float4*>(&s_T[kh][gR][aR][0]);

    for (int it = 1; it <= NITER; it++) {
        // thread-local softmax (log2 domain)
        float mx = lt[0];
        #pragma unroll
        for (int t = 1; t < MT; t++) mx = fmaxf(mx, lt[t]);
        float e[MT], ss = 0.f;
        #pragma unroll
        for (int t = 0; t < MT; t++) { e[t] = fexp2(lt[t] - mx); ss += e[t]; }
        float sc = P * frcp(ss);
        #pragma unroll
        for (int t = 0; t < MT; t++) e[t] *= sc;

        if (rvalid) {
            Trow[0] = make_float4(e[0], e[1], e[2], e[3]);
            Trow[1] = make_float4(e[4], e[5], e[6], e[7]);
            reinterpret_cast<float2*>(Trow)[4] = make_float2(e[8], e[9]);
        }
        __syncthreads();                         // (1) T visible

        // colsum -> q
        if (cvalid) {
            const float* colp = &s_T[ck][cn][0][ct];
            float s0 = 0.f;
            #pragma unroll
            for (int m = 0; m < MM; m++) s0 += colp[m * RS];
            qa = s0;
            s_q[ck][cn][ct] = s0;
        }
        __syncthreads();                         // (2) q visible
        if (it == NITER) break;

        // cc (cvalid threads; reads q of THEIR group)
        if (cvalid) {
            const float4* qp4 = reinterpret_cast<const float4*>(&s_q[ck][cn][0]);
            float4 qx = qp4[0], qy = qp4[1];
            float2 qz = reinterpret_cast<const float2*>(qp4)[4];
            const float4* cr = reinterpret_cast<const float4*>(&s_C2sq[ck][ct][0]);
            float4 ca = cr[0], cb = cr[1];
            float2 c2 = reinterpret_cast<const float2*>(cr)[4];
            float cc = qx.x * ca.x + qx.y * ca.y + qx.z * ca.z + qx.w * ca.w
                     + qy.x * cb.x + qy.y * cb.y + qy.z * cb.z + qy.w * cb.w
                     + qz.x * c2.x + qz.y * c2.y;
            s_cc[ck][cn][ct] = cc;
        }

        // row work: q read, Y1, y2 matvec, partial update (pre-ccr)
        float q[MT];
        {
            const float4* qp4 = reinterpret_cast<const float4*>(&s_q[kh][gR][0]);
            float4 qx = qp4[0], qy = qp4[1];
            float2 qz = reinterpret_cast<const float2*>(qp4)[4];
            q[0] = qx.x; q[1] = qx.y; q[2] = qx.z; q[3] = qx.w;
            q[4] = qy.x; q[5] = qy.y; q[6] = qy.z; q[7] = qy.w;
            q[8] = qz.x; q[9] = qz.y;
        }
        float y1[MT];
        #pragma unroll
        for (int t = 0; t < MT; t++) y1[t] = cmpl ? q[t] : 0.f;
        unsigned mm = lmask;
        while (mm) {
            int b = __ffs(mm) - 1;
            mm &= mm - 1;
            const float4* rb4 = reinterpret_cast<const float4*>(&s_T[kh][gR][b][0]);
            float4 ra = rb4[0], rb = rb4[1];
            float2 rc = reinterpret_cast<const float2*>(rb4)[4];
            y1[0] += sgn * ra.x; y1[1] += sgn * ra.y; y1[2] += sgn * ra.z; y1[3] += sgn * ra.w;
            y1[4] += sgn * rb.x; y1[5] += sgn * rb.y; y1[6] += sgn * rb.z; y1[7] += sgn * rb.w;
            y1[8] += sgn * rc.x; y1[9] += sgn * rc.y;
        }
        #pragma unroll
        for (int s = 0; s < MT; s++) {
            float y2 = 0.f;
            #pragma unroll
            for (int t = 0; t < MT; t++) y2 = fmaf(y1[t], c2p[s * MT + t], y2);
            lt[s] += tgl * y2 - Mc[s];           // ccr applied after barrier
        }
        __syncthreads();                         // (3) cc visible

        {
            const float4* cp = reinterpret_cast<const float4*>(&s_cc[kh][gR][0]);
            float4 ca = cp[0], cb = cp[1];
            float2 c2 = reinterpret_cast<const float2*>(cp)[4];
            lt[0] -= ca.x; lt[1] -= ca.y; lt[2] -= ca.z; lt[3] -= ca.w;
            lt[4] -= cb.x; lt[5] -= cb.y; lt[6] -= cb.z; lt[7] -= cb.w;
            lt[8] -= c2.x; lt[9] -= c2.y;
        }
    }

    if (cvalid) {
        int nOut = nb + cn;
        if (nOut < NN)
            out[(size_t)nOut * (NTPL * MT) + (kb + ck) * MT + ct] = qa;
    }
}

extern "C" void kernel_launch(void* const* d_in, const int* in_sizes, int n_in,
                              void* d_out, int out_size, void* d_ws, size_t ws_size,
                              hipStream_t stream) {
    const float* x      = (const float*)d_in[0];
    const int*   eidx   = (const int*)d_in[1];
    const float* tmpl   = (const float*)d_in[2];
    const float* tmplf  = (const float*)d_in[3];
    const float* alpha0 = (const float*)d_in[4];
    float*       outp   = (float*)d_out;

    const int* dst = eidx + NN * DEG;
    float* G = (float*)d_ws;
    const size_t gbytes = (size_t)NN * NTPL * MT * sizeof(float);
    int useG = (ws_size >= gbytes) ? 1 : 0;

    if (useG)
        gcost_kernel<<<dim3(NN / GNV, 20), dim3(256), 0, stream>>>(x, tmplf, alpha0, G);

    srfgw_kernel<<<dim3((NN + NPB - 1) / NPB, NTPL / KPB), dim3(BS), 0, stream>>>(
        x, dst, tmpl, tmplf, alpha0, G, useG, outp);
}

// Round 14
// 203.609 us; speedup vs baseline: 1.2332x; 1.0230x over previous
//
#include <hip/hip_runtime.h>

// LTFGW semi-relaxed FGW — round 14: gcost v5 (isolated change).
// Gap ledger (total - srfgw): 53,56,61,66,65,67 us r5->r13 — the serialized
//   gcost kernel. v3's flaw: a ds_swizzle (DS pipe, ~64+cyc) in EVERY node
//   iteration's dependency chain. v5: 16 lanes per kt -> 8 floats/lane ->
//   the reduce is 4 DPP row_ror adds ONLY (no cross-row, no LDS, no swizzle).
//   Per node: 2 coalesced float4 loads + 8 FMA + 4 DPP + 1 store (4 lane-0
//   stores/wave coalesce to one 16B line). unroll 4 = 4 independent chains.
// srfgw: BYTE-IDENTICAL to round 13 (141.5 us; flat 119/128 packing,
//   LDS colsum q, iter-0 fold, native exp2/rcp, log2 domain).

#define NN    6000
#define DEG   16
#define MM    17
#define NTPL  16
#define MT    10
#define NF    128
#define NITER 10
#define KPB   4
#define NPB   7
#define BS    512
#define RS    12            // padded T row stride (floats)
#define LOG2E 1.44269504088896340736f

template<int C>
__device__ __forceinline__ float ror_add(float v) {
    int s = __builtin_amdgcn_update_dpp(0, __float_as_int(v), C, 0xf, 0xf, true);
    return v + __int_as_float(s);
}

__device__ __forceinline__ float fexp2(float x) { return __builtin_amdgcn_exp2f(x); }
__device__ __forceinline__ float frcp(float x)  { return __builtin_amdgcn_rcpf(x); }

// sum over each 16-lane row (all lanes get the sum) — pure VALU DPP
__device__ __forceinline__ float reduce16(float v) {
    v = ror_add<0x121>(v);
    v = ror_add<0x122>(v);
    v = ror_add<0x124>(v);
    v = ror_add<0x128>(v);
    return v;
}

// ---------------- gcost v5: G[v,kt] = mcoefl*(||F2[kt]||^2 - 2 x[v].F2[kt])
// 16 lanes per kt; F2 chunk (8 floats) in registers; row-local DPP reduce.
#define GNV 40
__global__ __launch_bounds__(256) void gcost_kernel(
    const float* __restrict__ x, const float* __restrict__ F2g,
    const float* __restrict__ alpha0, float* __restrict__ G)
{
    const int kt  = blockIdx.y * 16 + (threadIdx.x >> 4);   // grid.y=10 -> 0..159
    const int l16 = threadIdx.x & 15;

    const float4* f2p = reinterpret_cast<const float4*>(F2g + (size_t)kt * NF) + l16 * 2;
    const float4 f2a = f2p[0], f2b = f2p[1];
    float sq = reduce16(f2a.x * f2a.x + f2a.y * f2a.y + f2a.z * f2a.z + f2a.w * f2a.w
                      + f2b.x * f2b.x + f2b.y * f2b.y + f2b.z * f2b.z + f2b.w * f2b.w);

    const float alpha  = 1.f / (1.f + __expf(-alpha0[0]));
    const float mcoefl = (1.f - alpha) * 10.f * LOG2E;
    const float base   = mcoefl * sq;
    const float m2     = -2.f * mcoefl;

    const int v0 = blockIdx.x * GNV;
    #pragma unroll 4
    for (int i = 0; i < GNV; i++) {
        const int v = v0 + i;
        const float4* xp = reinterpret_cast<const float4*>(x + (size_t)v * NF) + l16 * 2;
        float4 xa = xp[0], xb = xp[1];
        float d = xa.x * f2a.x + xa.y * f2a.y + xa.z * f2a.z + xa.w * f2a.w
                + xb.x * f2b.x + xb.y * f2b.y + xb.z * f2b.z + xb.w * f2b.w;
        d = reduce16(d);
        if (l16 == 0)
            G[(size_t)v * (NTPL * MT) + kt] = fmaf(m2, d, base);
    }
}

// ---------------- main kernel (round-13 verbatim)
__global__ __launch_bounds__(BS, 4) void srfgw_kernel(
    const float* __restrict__ x,
    const int*   __restrict__ dst,
    const float* __restrict__ C2g,
    const float* __restrict__ F2g,
    const float* __restrict__ alpha0,
    const float* __restrict__ G,
    int useG,
    float*       __restrict__ out)
{
    const int nb  = blockIdx.x * NPB;
    const int kb  = blockIdx.y * KPB;
    const int tid = threadIdx.x;

    __shared__ __align__(16) float s_T[KPB][NPB][MM][RS];     // 22848 B
    __shared__ __align__(16) float s_C2sq[KPB][MT][RS];       // 1920 B
    __shared__ __align__(16) float s_q[KPB][NPB][RS];         // 1344 B
    __shared__ __align__(16) float s_cc[KPB][NPB][RS];        // 1344 B
    __shared__ __align__(16) float s_A[KPB][RS];              // 192 B
    __shared__ __align__(16) float s_B[KPB][RS];              // 192 B
    __shared__ __align__(16) int   s_adj[NPB * MM][DEG];      // 7616 B
    __shared__ int      s_nbr[NPB][MM];
    __shared__ unsigned s_mask[NPB][MM];

    const float aval  = alpha0[0];
    const float alpha = 1.f / (1.f + __expf(-aval));
    const float gcoef = 2.f * alpha * 10.f;
    const float tgl   = 2.f * gcoef * LOG2E;
    const float gl2   = gcoef * LOG2E;

    // nbr (119 <= BS); node clamp: 7 does not divide 6000
    if (tid < NPB * MM) {
        int node = tid / MM, a0 = tid - node * MM;
        int nd  = nb + node;
        int ndc = nd < NN ? nd : NN - 1;
        s_nbr[node][a0]  = (a0 == 0) ? ndc : dst[(size_t)ndc * DEG + a0 - 1];
        s_mask[node][a0] = 0u;
    }
    __syncthreads();

    // adjacency rows (1904 > BS -> strided)
    for (int i = tid; i < NPB * MM * DEG; i += BS) {
        int r = i >> 4, j = i & 15;
        int node = r / MM, a0 = r - node * MM;
        s_adj[r][j] = dst[(size_t)s_nbr[node][a0] * DEG + j];
    }
    // C2sq (strided; kb offset)
    for (int i = tid; i < KPB * MT * MT; i += BS) {
        int kk = i / (MT * MT), rr = i - kk * (MT * MT);
        int rs = rr / MT, rt = rr - rs * MT;
        float v = C2g[(size_t)kb * MT * MT + i];
        s_C2sq[kk][rs][rt] = gl2 * v * v;
    }
    // iter-0 fold constants (40 <= BS)
    if (tid < KPB * MT) {
        int kk = tid / MT, s = tid - kk * MT;
        const float* cr = C2g + (size_t)(kb + kk) * MT * MT + s * MT;
        float rs = 0.f, rq = 0.f;
        #pragma unroll
        for (int t = 0; t < MT; t++) { float c = cr[t]; rs += c; rq = fmaf(c, c, rq); }
        s_A[kk][s] = (tgl / 170.f) * rs;
        s_B[kk][s] = 0.1f * gl2 * rq;
    }
    __syncthreads();

    // masks (2023 > BS -> strided), dual atomicOr symmetrization
    for (int i = tid; i < NPB * MM * MM; i += BS) {
        int node = i / (MM * MM), rr = i - node * (MM * MM);
        int pa = rr / MM, pb = rr - pa * MM;
        int vtgt = s_nbr[node][pb];
        const int* ar = s_adj[node * MM + pa];
        bool e = false;
        #pragma unroll
        for (int j = 0; j < DEG; j++) e = e | (ar[j] == vtgt);
        if (e) {
            atomicOr(&s_mask[node][pa], 1u << pb);
            atomicOr(&s_mask[node][pb], 1u << pa);
        }
    }
    __syncthreads();

    // ---- row mapping: kh wave-uniform; 119 rows flat-packed in 128 lanes ----
    const int  kh     = tid >> 7;              // 0..3
    const int  L      = tid & 127;
    const bool rvalid = L < NPB * MM;          // 119
    int gR = L / MM;
    int aR = L - gR * MM;
    if (!rvalid) { gR = 0; aR = 0; }

    const int k_u = __builtin_amdgcn_readfirstlane(kb + kh);
    const float* __restrict__ c2p = C2g + (size_t)k_u * MT * MT;

    const int vv = s_nbr[gR][aR];

    float Mc[MT];
    if (useG) {
        const float2* gp = reinterpret_cast<const float2*>(G + (size_t)vv * (NTPL * MT) + k_u * MT);
        #pragma unroll
        for (int j = 0; j < 5; j++) {
            float2 w = gp[j];
            Mc[2 * j] = w.x; Mc[2 * j + 1] = w.y;
        }
    } else {
        float dot[MT], sq2[MT];
        #pragma unroll
        for (int t = 0; t < MT; t++) { dot[t] = 0.f; sq2[t] = 0.f; }
        const float4* xr = reinterpret_cast<const float4*>(x + (size_t)vv * NF);
        const float4* fr = reinterpret_cast<const float4*>(F2g + (size_t)k_u * MT * NF);
        for (int f = 0; f < NF / 4; f++) {
            float4 xa = xr[f];
            #pragma unroll
            for (int t = 0; t < MT; t++) {
                float4 b = fr[t * (NF / 4) + f];
                dot[t] += xa.x * b.x + xa.y * b.y + xa.z * b.z + xa.w * b.w;
                sq2[t] += b.x * b.x + b.y * b.y + b.z * b.z + b.w * b.w;
            }
        }
        const float mcoefl = (1.f - alpha) * 10.f * LOG2E;
        #pragma unroll
        for (int t = 0; t < MT; t++) Mc[t] = mcoefl * (sq2[t] - 2.f * dot[t]);
    }

    unsigned mask = rvalid ? s_mask[gR][aR] : 0u;
    const int  pcnt = __popc(mask);
    const bool cmpl = pcnt > 8;
    unsigned   lmask = cmpl ? (~mask & 0x1FFFFu) : mask;
    if (!rvalid) lmask = 0u;
    const float sgn = cmpl ? -1.f : 1.f;
    const float P   = 1.f / 17.f;

    // ---- iter-0 analytic fold ----
    float lt[MT];
    {
        const float pcf = (float)pcnt;
        const float2* Ap = reinterpret_cast<const float2*>(&s_A[kh][0]);
        const float2* Bp = reinterpret_cast<const float2*>(&s_B[kh][0]);
        #pragma unroll
        for (int j = 0; j < 5; j++) {
            float2 av = Ap[j], bv = Bp[j];
            lt[2 * j]     = fmaf(pcf, av.x, -bv.x - Mc[2 * j]);
            lt[2 * j + 1] = fmaf(pcf, av.y, -bv.y - Mc[2 * j + 1]);
        }
    }

    // ---- colsum/cc mapping: tid < 280 -> (ck, cn, ct) ----
    const bool cvalid = tid < KPB * NPB * MT;  // 280
    int ck = 0, cn = 0, ct = 0;
    if (cvalid) {
        ck = tid / (NPB * MT);
        int rem = tid - ck * (NPB * MT);
        cn = rem / MT;
        ct = rem - cn * MT;
    }
    float qa = 0.f;

    float4* Trow = reinterpret_cast<float4*>(&s_T[kh][gR][aR][0]);

    for (int it = 1; it <= NITER; it++) {
        // thread-local softmax (log2 domain)
        float mx = lt[0];
        #pragma unroll
        for (int t = 1; t < MT; t++) mx = fmaxf(mx, lt[t]);
        float e[MT], ss = 0.f;
        #pragma unroll
        for (int t = 0; t < MT; t++) { e[t] = fexp2(lt[t] - mx); ss += e[t]; }
        float sc = P * frcp(ss);
        #pragma unroll
        for (int t = 0; t < MT; t++) e[t] *= sc;

        if (rvalid) {
            Trow[0] = make_float4(e[0], e[1], e[2], e[3]);
            Trow[1] = make_float4(e[4], e[5], e[6], e[7]);
            reinterpret_cast<float2*>(Trow)[4] = make_float2(e[8], e[9]);
        }
        __syncthreads();                         // (1) T visible

        // colsum -> q
        if (cvalid) {
            const float* colp = &s_T[ck][cn][0][ct];
            float s0 = 0.f;
            #pragma unroll
            for (int m = 0; m < MM; m++) s0 += colp[m * RS];
            qa = s0;
            s_q[ck][cn][ct] = s0;
        }
        __syncthreads();                         // (2) q visible
        if (it == NITER) break;

        // cc (cvalid threads)
        if (cvalid) {
            const float4* qp4 = reinterpret_cast<const float4*>(&s_q[ck][cn][0]);
            float4 qx = qp4[0], qy = qp4[1];
            float2 qz = reinterpret_cast<const float2*>(qp4)[4];
            const float4* cr = reinterpret_cast<const float4*>(&s_C2sq[ck][ct][0]);
            float4 ca = cr[0], cb = cr[1];
            float2 c2 = reinterpret_cast<const float2*>(cr)[4];
            float cc = qx.x * ca.x + qx.y * ca.y + qx.z * ca.z + qx.w * ca.w
                     + qy.x * cb.x + qy.y * cb.y + qy.z * cb.z + qy.w * cb.w
                     + qz.x * c2.x + qz.y * c2.y;
            s_cc[ck][cn][ct] = cc;
        }

        // row work: q read, Y1, y2 matvec, partial update (pre-ccr)
        float q[MT];
        {
            const float4* qp4 = reinterpret_cast<const float4*>(&s_q[kh][gR][0]);
            float4 qx = qp4[0], qy = qp4[1];
            float2 qz = reinterpret_cast<const float2*>(qp4)[4];
            q[0] = qx.x; q[1] = qx.y; q[2] = qx.z; q[3] = qx.w;
            q[4] = qy.x; q[5] = qy.y; q[6] = qy.z; q[7] = qy.w;
            q[8] = qz.x; q[9] = qz.y;
        }
        float y1[MT];
        #pragma unroll
        for (int t = 0; t < MT; t++) y1[t] = cmpl ? q[t] : 0.f;
        unsigned mm = lmask;
        while (mm) {
            int b = __ffs(mm) - 1;
            mm &= mm - 1;
            const float4* rb4 = reinterpret_cast<const float4*>(&s_T[kh][gR][b][0]);
            float4 ra = rb4[0], rb = rb4[1];
            float2 rc = reinterpret_cast<const float2*>(rb4)[4];
            y1[0] += sgn * ra.x; y1[1] += sgn * ra.y; y1[2] += sgn * ra.z; y1[3] += sgn * ra.w;
            y1[4] += sgn * rb.x; y1[5] += sgn * rb.y; y1[6] += sgn * rb.z; y1[7] += sgn * rb.w;
            y1[8] += sgn * rc.x; y1[9] += sgn * rc.y;
        }
        #pragma unroll
        for (int s = 0; s < MT; s++) {
            float y2 = 0.f;
            #pragma unroll
            for (int t = 0; t < MT; t++) y2 = fmaf(y1[t], c2p[s * MT + t], y2);
            lt[s] += tgl * y2 - Mc[s];           // ccr applied after barrier
        }
        __syncthreads();                         // (3) cc visible

        {
            const float4* cp = reinterpret_cast<const float4*>(&s_cc[kh][gR][0]);
            float4 ca = cp[0], cb = cp[1];
            float2 c2 = reinterpret_cast<const float2*>(cp)[4];
            lt[0] -= ca.x; lt[1] -= ca.y; lt[2] -= ca.z; lt[3] -= ca.w;
            lt[4] -= cb.x; lt[5] -= cb.y; lt[6] -= cb.z; lt[7] -= cb.w;
            lt[8] -= c2.x; lt[9] -= c2.y;
        }
    }

    if (cvalid) {
        int nOut = nb + cn;
        if (nOut < NN)
            out[(size_t)nOut * (NTPL * MT) + (kb + ck) * MT + ct] = qa;
    }
}

extern "C" void kernel_launch(void* const* d_in, const int* in_sizes, int n_in,
                              void* d_out, int out_size, void* d_ws, size_t ws_size,
                              hipStream_t stream) {
    const float* x      = (const float*)d_in[0];
    const int*   eidx   = (const int*)d_in[1];
    const float* tmpl   = (const float*)d_in[2];
    const float* tmplf  = (const float*)d_in[3];
    const float* alpha0 = (const float*)d_in[4];
    float*       outp   = (float*)d_out;

    const int* dst = eidx + NN * DEG;
    float* G = (float*)d_ws;
    const size_t gbytes = (size_t)NN * NTPL * MT * sizeof(float);
    int useG = (ws_size >= gbytes) ? 1 : 0;

    if (useG)
        gcost_kernel<<<dim3(NN / GNV, 10), dim3(256), 0, stream>>>(x, tmplf, alpha0, G);

    srfgw_kernel<<<dim3((NN + NPB - 1) / NPB, NTPL / KPB), dim3(BS), 0, stream>>>(
        x, dst, tmpl, tmplf, alpha0, G, useG, outp);
}